// Round 1
// baseline (27.451 us; speedup 1.0000x reference)
//
#include <hip/hip_runtime.h>
#include <math.h>

// AttentionCropLayer: out[b,c,i,j] = images[b,c,w_off+i,h_off+j] * prof[i]*prof[j]
//   tx = clip(locs[b,0]*224, 44, 180); w_off = floor(tx-44)   (same for h via locs[b,1])
//   prof[r] = sigmoid(10*r) - sigmoid(10*(r-88))
// Shapes: images [128,16,224,224] f32, locs [128,2] f32, out [128,16,88,88] f32.
// Memory-bound: ~63 MB read + ~63 MB write.

#define TLn   44
#define CROP  88
#define INSZ  224
#define NCH   16
#define PLANE (CROP * CROP)     // 7744
#define QPLANE (PLANE / 4)      // 1936 float4 per plane

__global__ __launch_bounds__(256)
void attention_crop_kernel(const float* __restrict__ images,
                           const float* __restrict__ locs,
                           float* __restrict__ out)
{
    __shared__ float prof[CROP];
    __shared__ int   offs[2];

    const int bc = blockIdx.x;        // b * NCH + c
    const int b  = bc >> 4;
    const int t  = threadIdx.x;

    // Mask profile (identical for all blocks; 88 expf's per block is negligible).
    if (t < CROP) {
        float r  = (float)t;
        float s1 = 1.0f / (1.0f + expf(-10.0f * r));
        float s2 = 1.0f / (1.0f + expf(-10.0f * (r - (float)CROP)));
        prof[t] = s1 - s2;
    }
    // Per-batch crop offsets — same float32 arithmetic as the reference.
    if (t == 0) {
        float tx = fminf(fmaxf(locs[2 * b]     * 224.0f, (float)TLn), (float)(INSZ - TLn));
        float ty = fminf(fmaxf(locs[2 * b + 1] * 224.0f, (float)TLn), (float)(INSZ - TLn));
        offs[0] = (int)floorf(tx - (float)TLn);   // value in [0,136], trunc == floor
        offs[1] = (int)floorf(ty - (float)TLn);
    }
    __syncthreads();

    const int w_off = offs[0];
    const int h_off = offs[1];

    const float* __restrict__ src =
        images + ((size_t)bc * INSZ + (size_t)w_off) * INSZ + h_off;
    float* __restrict__ dst = out + (size_t)bc * PLANE;

    // Each thread: 4 consecutive output floats per iteration (never crosses a
    // crop row since 88 % 4 == 0). Input is only 4B-aligned (h_off arbitrary)
    // -> scalar loads; output plane base is 16B-aligned -> float4 store.
    for (int q = t; q < QPLANE; q += 256) {
        const int e = q * 4;
        const int i = e / CROP;
        const int j = e - i * CROP;

        const float* __restrict__ s = src + (size_t)i * INSZ + j;
        float4 v;
        v.x = s[0];
        v.y = s[1];
        v.z = s[2];
        v.w = s[3];

        const float pi = prof[i];
        v.x *= pi * prof[j];
        v.y *= pi * prof[j + 1];
        v.z *= pi * prof[j + 2];
        v.w *= pi * prof[j + 3];

        *reinterpret_cast<float4*>(dst + e) = v;
    }
}

extern "C" void kernel_launch(void* const* d_in, const int* in_sizes, int n_in,
                              void* d_out, int out_size, void* d_ws, size_t ws_size,
                              hipStream_t stream)
{
    const float* images = (const float*)d_in[0];
    const float* locs   = (const float*)d_in[1];
    float*       out    = (float*)d_out;

    const int B = in_sizes[1] / 2;     // 128
    dim3 grid(B * NCH);                // 2048 blocks, one per (b, c) plane
    attention_crop_kernel<<<grid, 256, 0, stream>>>(images, locs, out);
}